// Round 3
// baseline (754.048 us; speedup 1.0000x reference)
//
#include <hip/hip_runtime.h>
#include <stdint.h>

#define FEAT 256
#define CODES 8192
#define NQ 16384                 // 16*32*32
#define ZQ_ELEMS (NQ * FEAT)
#define MARGIN 2e-3f             // = 2e bound on fp16 score error (R4-validated)
#define NSLICE 8
#define CAP_PAIRS (1 << 18)      // 256K (expected ~25-50K with fused push)
#define KSC (-0.0078125f)        // descale: acc * -2/256

typedef _Float16 f16x8 __attribute__((ext_vector_type(8)));
typedef float f32x4 __attribute__((ext_vector_type(4)));

__device__ __forceinline__ void async_lds16(void* lds, const void* g) {
  __builtin_amdgcn_global_load_lds(
      (const __attribute__((address_space(1))) void*)(uintptr_t)(g),
      (__attribute__((address_space(3))) void*)(uint32_t)(uintptr_t)(lds),
      16, 0, 0);
}

// monotone float<->uint order transform
__device__ __forceinline__ unsigned f2mono(float v) {
  unsigned u = __float_as_uint(v);
  return (u & 0x80000000u) ? ~u : (u | 0x80000000u);
}
__device__ __forceinline__ float mono2f(unsigned t) {
  unsigned u = (t & 0x80000000u) ? (t & 0x7fffffffu) : ~t;
  return __uint_as_float(u);
}

// ---------------------------------------------------------------------------
// numpy pairwise sum-of-squares replication (verified R1-R4, absmax 0).
// ---------------------------------------------------------------------------
template <int STRIDE>
__device__ __forceinline__ float pairwise256_sq(const float* __restrict__ base, int lane16) {
  const int h = lane16 >> 3, j = lane16 & 7;
  const float* p = base + (h * 128 + j) * STRIDE;
  float x = p[0];
  float r = __fmul_rn(x, x);
#pragma unroll
  for (int i = 1; i < 16; ++i) {
    float y = p[i * 8 * STRIDE];
    r = __fadd_rn(r, __fmul_rn(y, y));
  }
  r = __fadd_rn(r, __shfl_xor(r, 1, 64));
  r = __fadd_rn(r, __shfl_xor(r, 2, 64));
  r = __fadd_rn(r, __shfl_xor(r, 4, 64));
  float other = __shfl_xor(r, 8, 64);
  float lo = (h == 0) ? r : other;
  float hi = (h == 0) ? other : r;
  return __fadd_rn(lo, hi);
}

__global__ __launch_bounds__(256) void norms_kernel(const float* __restrict__ cb,
                                                    const float* __restrict__ z,
                                                    float* __restrict__ cbnorm,
                                                    float* __restrict__ znorm) {
  const int g = (blockIdx.x * 256 + threadIdx.x) >> 4;
  const int lane16 = threadIdx.x & 15;
  if (g < CODES) {
    float v = pairwise256_sq<1>(cb + g * FEAT, lane16);
    if (lane16 == 0) cbnorm[g] = v;
  } else {
    const int q = g - CODES;
    const int b = q >> 10, hw = q & 1023;
    float v = pairwise256_sq<1024>(z + b * (FEAT * 1024) + hw, lane16);
    if (lane16 == 0) znorm[q] = v;
  }
}

// ---------------------------------------------------------------------------
// convA: z fp32 -> fp16 tiles [mt][ct][r128][c32] + fp32 transpose zT[q][c]
// ---------------------------------------------------------------------------
__global__ __launch_bounds__(256) void convA(const float* __restrict__ z,
                                             char* __restrict__ At, float* __restrict__ zT) {
  __shared__ _Float16 T[128 * 40];
  __shared__ float Tf[128 * 36];
  const int t = threadIdx.x;
  const int mt = blockIdx.x >> 3, ct = blockIdx.x & 7;
  const int q0 = mt * 128, bb = q0 >> 10, hw0 = q0 & 1023;
  const int c0 = ct * 32;
#pragma unroll
  for (int it = 0; it < 16; ++it) {
    const int cc = it * 2 + (t >> 7);
    const int qi = t & 127;
    float v = z[bb * (FEAT * 1024) + (c0 + cc) * 1024 + hw0 + qi];
    T[qi * 40 + cc] = (_Float16)v;
    Tf[qi * 36 + cc] = v;
  }
  __syncthreads();
  const int r = t >> 1, h = t & 1;
  {
    float4 a = *(const float4*)&T[r * 40 + h * 16];
    float4 b = *(const float4*)&T[r * 40 + h * 16 + 8];
    char* dst = At + (size_t)(mt * 8 + ct) * 8192 + t * 32;
    *(float4*)dst = a;
    *(float4*)(dst + 16) = b;
  }
  float* zrow = zT + (size_t)(q0 + r) * FEAT + c0 + h * 16;
#pragma unroll
  for (int e = 0; e < 4; ++e)
    *(float4*)(zrow + e * 4) = *(const float4*)&Tf[r * 36 + h * 16 + e * 4];
}

// ---------------------------------------------------------------------------
// convB: cb fp32 -> fp16 FRAGMENT-LINEAR layout, scaled by 256.
// For chunk cg = nt*8+ct, wn in {0,1}, j in [0,4): a contiguous 1KB block of
// 64 lanes x 16B where lane l holds
//   f16(cb[nt*128 + wn*64 + j*16 + (l&15)][ct*32 + (l>>4)*8 .. +8] * 256)
// ---------------------------------------------------------------------------
__global__ __launch_bounds__(256) void convB(const float* __restrict__ cb, char* __restrict__ Bt) {
  const int T = blockIdx.x * 256 + threadIdx.x;   // [0, 131072)
  const int K = T >> 4, part = T & 15;            // K: code row; part: 16-float chunk
  const float* src = cb + (size_t)K * FEAT + part * 16;
  const int nt = K >> 7, rem = K & 127;
  const int wn = rem >> 6, j = (rem >> 4) & 3, llo = rem & 15;
#pragma unroll
  for (int g = 0; g < 2; ++g) {
    const int c0 = part * 16 + g * 8;
    const int ct = c0 >> 5, lhi = (c0 >> 3) & 3;
    const int cg = nt * 8 + ct;
    f16x8 o;
#pragma unroll
    for (int e = 0; e < 8; ++e) o[e] = (_Float16)(src[g * 8 + e] * 256.0f);
    const size_t s = ((size_t)((cg * 2 + wn) * 4 + j) << 6) + (size_t)(lhi * 16 + llo);
    *(f16x8*)(Bt + s * 16) = o;
  }
}

// ---------------------------------------------------------------------------
// FUSED single-pass GEMM: per nt-tile, compute scores, cross-col tile min,
// post running min via atomicMin(gmin) (RMW return = coherent cross-XCD
// snapshot), set thr = min(snapshot, local_run_min) + MARGIN, and push
// candidates s <= thr. thr >= gmin_final + MARGIN always, so the pushed set
// is a superset of the two-pass candidate set; exact_cand rescore gives the
// identical deterministic winner. Tile 0 push is deferred one tile (acc held
// in registers) so it uses the cross-slice-informed tile-1 threshold.
// ---------------------------------------------------------------------------
__global__ __launch_bounds__(256, 2) void gemm_fused(const char* __restrict__ At,
                                                     const char* __restrict__ Bt,
                                                     const float* __restrict__ cbnorm,
                                                     unsigned* __restrict__ gmin,
                                                     unsigned* __restrict__ pairs,
                                                     int* __restrict__ paircount) {
  __shared__ __align__(16) char Af[65536];
  __shared__ __align__(16) char Bs0[8192];
  __shared__ __align__(16) char Bs1[8192];

  const int tid = threadIdx.x;
  const int slice = blockIdx.x & 7, mt = blockIdx.x >> 3;
  const int wave = tid >> 6, lane = tid & 63;
  const int wm = wave >> 1, wn = wave & 1;
  const int col = lane & 15;

  const int srow = wave * 32 + (lane >> 2);  // A staging row within 32-row group
  const int ss = lane & 3;
  const char* Abase = At + (size_t)(mt * 8) * 8192;
  const char* Bslice = Bt + (size_t)slice * 524288;

  // stage entire A tile (8 ct-chunks) into LDS, swizzled slots
#pragma unroll
  for (int ct = 0; ct < 8; ++ct) {
#pragma unroll
    for (int i = 0; i < 2; ++i) {
      const int r = srow + i * 16;
      const int cs = ss ^ ((r >> 1) & 3);
      async_lds16(Af + ct * 8192 + wave * 2048 + i * 1024,
                  Abase + (size_t)ct * 8192 + r * 64 + cs * 16);
    }
  }

#define STAGE_B(BUF, CIDX)                                                          \
  do {                                                                              \
    const char* gs_ = Bslice + ((size_t)(CIDX) << 13) + wave * 2048 + lane * 16;    \
    async_lds16((BUF) + wave * 2048, gs_);                                          \
    async_lds16((BUF) + wave * 2048 + 1024, gs_ + 1024);                            \
  } while (0)

  // prime double-buffer: chunks 0 and 1
  STAGE_B(Bs0, 0);
  STAGE_B(Bs1, 1);

  int aoff[4];
#pragma unroll
  for (int i = 0; i < 4; ++i) {
    const int m = wm * 64 + i * 16 + col;
    const int quad_ = lane >> 4;
    aoff[i] = m * 64 + ((quad_ ^ ((m >> 1) & 3)) << 4);
  }

  int qrow[16];
#pragma unroll
  for (int row = 0; row < 16; ++row)
    qrow[row] = mt * 128 + wm * 64 + (row >> 2) * 16 + (lane >> 4) * 4 + (row & 3);

  float vrun[16], thr[16], rm[16], cn[4];
#pragma unroll
  for (int row = 0; row < 16; ++row) vrun[row] = 3.4e38f;

  f32x4 acc[4][4], accH[4][4];

  __syncthreads();  // full drain once: A tile + B chunks 0,1 landed

  // Per-chunk step. WMODE 2: s_waitcnt vmcnt(2) -- the 2 newest outstanding
  // VMEM ops are this chunk's stage; everything older (incl. next chunk's
  // buffer AND any scoring loads/atomics) is complete. 0: drain. 3: no wait.
#define CHUNK(CT, STG, CNEXT, WMODE)                                                \
  do {                                                                              \
    char* Bcur_ = ((CT) & 1) ? Bs1 : Bs0;                                           \
    f16x8 bf_[4], af_[4];                                                           \
    _Pragma("unroll") for (int j = 0; j < 4; ++j)                                   \
        bf_[j] = *(const f16x8*)(Bcur_ + wn * 4096 + j * 1024 + lane * 16);         \
    _Pragma("unroll") for (int i = 0; i < 4; ++i)                                   \
        af_[i] = *(const f16x8*)(Af + (CT) * 8192 + aoff[i]);                       \
    asm volatile("s_waitcnt lgkmcnt(0)" ::: "memory");                              \
    __builtin_amdgcn_sched_barrier(0);                                              \
    __builtin_amdgcn_s_barrier(); /* all waves done reading Bcur_ */                \
    if (STG) {                                                                      \
      STAGE_B(Bcur_, CNEXT);                                                        \
      __builtin_amdgcn_sched_barrier(0); /* keep loads issued before MFMA */        \
    }                                                                               \
    _Pragma("unroll") for (int i = 0; i < 4; ++i)                                   \
        _Pragma("unroll") for (int j = 0; j < 4; ++j)                               \
            acc[i][j] = __builtin_amdgcn_mfma_f32_16x16x32_f16(af_[i], bf_[j],      \
                                                               acc[i][j], 0, 0, 0); \
    if ((WMODE) == 2) {                                                             \
      asm volatile("s_waitcnt vmcnt(2)" ::: "memory");                              \
      __builtin_amdgcn_sched_barrier(0);                                            \
    }                                                                               \
    if ((WMODE) == 0) {                                                             \
      asm volatile("s_waitcnt vmcnt(0)" ::: "memory");                              \
      __builtin_amdgcn_sched_barrier(0);                                            \
    }                                                                               \
    __builtin_amdgcn_s_barrier(); /* next buffer staged for all waves */            \
  } while (0)

#define ZEROACC                                                                     \
  do {                                                                              \
    _Pragma("unroll") for (int i = 0; i < 4; ++i)                                   \
        _Pragma("unroll") for (int j = 0; j < 4; ++j)                               \
            acc[i][j] = (f32x4){0.f, 0.f, 0.f, 0.f};                                \
  } while (0)

  // per-tile: rm (own-col row min), cross-col tile min, running min post via
  // atomicMin (returns coherent global snapshot), broadcast thr to col group.
#define TILE_SCORE(NT)                                                              \
  do {                                                                              \
    const int kb_ = (slice * 8 + (NT)) * 128;                                       \
    _Pragma("unroll") for (int j = 0; j < 4; ++j)                                   \
        cn[j] = cbnorm[kb_ + wn * 64 + j * 16 + col];                               \
    _Pragma("unroll") for (int i = 0; i < 4; ++i)                                   \
        _Pragma("unroll") for (int r = 0; r < 4; ++r) {                             \
      const int row_ = i * 4 + r;                                                   \
      const float s0_ = __builtin_fmaf(acc[i][0][r], KSC, cn[0]);                   \
      const float s1_ = __builtin_fmaf(acc[i][1][r], KSC, cn[1]);                   \
      const float s2_ = __builtin_fmaf(acc[i][2][r], KSC, cn[2]);                   \
      const float s3_ = __builtin_fmaf(acc[i][3][r], KSC, cn[3]);                   \
      rm[row_] = fminf(fminf(s0_, s1_), fminf(s2_, s3_));                           \
      float tm_ = rm[row_];                                                         \
      tm_ = fminf(tm_, __shfl_xor(tm_, 1, 64));                                     \
      tm_ = fminf(tm_, __shfl_xor(tm_, 2, 64));                                     \
      tm_ = fminf(tm_, __shfl_xor(tm_, 4, 64));                                     \
      tm_ = fminf(tm_, __shfl_xor(tm_, 8, 64));                                     \
      vrun[row_] = fminf(vrun[row_], tm_);                                          \
    }                                                                               \
    float thrv_[16];                                                                \
    _Pragma("unroll") for (int row_ = 0; row_ < 16; ++row_)                         \
        thrv_[row_] = vrun[row_];                                                   \
    if (col == 0) {                                                                 \
      unsigned oldv_[16];                                                           \
      _Pragma("unroll") for (int row_ = 0; row_ < 16; ++row_)                       \
          oldv_[row_] = atomicMin(&gmin[qrow[row_]], f2mono(vrun[row_]));           \
      _Pragma("unroll") for (int row_ = 0; row_ < 16; ++row_)                       \
          thrv_[row_] = fminf(mono2f(oldv_[row_]), vrun[row_]);                     \
    }                                                                               \
    _Pragma("unroll") for (int row_ = 0; row_ < 16; ++row_)                         \
        thr[row_] = __shfl(thrv_[row_], lane & 48, 64) + MARGIN;                    \
  } while (0)

#define PUSH_CUR(NT)                                                                \
  do {                                                                              \
    const int kb_ = (slice * 8 + (NT)) * 128;                                       \
    _Pragma("unroll") for (int i = 0; i < 4; ++i)                                   \
        _Pragma("unroll") for (int r = 0; r < 4; ++r) {                             \
      const int row_ = i * 4 + r;                                                   \
      if (rm[row_] <= thr[row_]) {                                                  \
        _Pragma("unroll") for (int j = 0; j < 4; ++j) {                             \
          const float s_ = __builtin_fmaf(acc[i][j][r], KSC, cn[j]);                \
          if (s_ <= thr[row_]) {                                                    \
            const int slot_ = atomicAdd(paircount, 1);                              \
            if (slot_ < CAP_PAIRS)                                                  \
              pairs[slot_] = ((unsigned)qrow[row_] << 13) |                         \
                             (unsigned)(kb_ + wn * 64 + j * 16 + col);              \
          }                                                                         \
        }                                                                           \
      }                                                                             \
    }                                                                               \
  } while (0)

  // deferred tile-0 push (from held acc, scores recomputed; thr is tile-1's,
  // which is tighter and still >= gmin_final + MARGIN)
#define PUSH_DEFER                                                                  \
  do {                                                                              \
    const int kb_ = slice * 8 * 128;                                                \
    float cn0_[4];                                                                  \
    _Pragma("unroll") for (int j = 0; j < 4; ++j)                                   \
        cn0_[j] = cbnorm[kb_ + wn * 64 + j * 16 + col];                             \
    _Pragma("unroll") for (int i = 0; i < 4; ++i)                                   \
        _Pragma("unroll") for (int r = 0; r < 4; ++r) {                             \
      const int row_ = i * 4 + r;                                                   \
      const float s0_ = __builtin_fmaf(accH[i][0][r], KSC, cn0_[0]);                \
      const float s1_ = __builtin_fmaf(accH[i][1][r], KSC, cn0_[1]);                \
      const float s2_ = __builtin_fmaf(accH[i][2][r], KSC, cn0_[2]);                \
      const float s3_ = __builtin_fmaf(accH[i][3][r], KSC, cn0_[3]);                \
      if (fminf(fminf(s0_, s1_), fminf(s2_, s3_)) <= thr[row_]) {                   \
        const float sv_[4] = {s0_, s1_, s2_, s3_};                                  \
        _Pragma("unroll") for (int j = 0; j < 4; ++j) {                             \
          if (sv_[j] <= thr[row_]) {                                                \
            const int slot_ = atomicAdd(paircount, 1);                              \
            if (slot_ < CAP_PAIRS)                                                  \
              pairs[slot_] = ((unsigned)qrow[row_] << 13) |                         \
                             (unsigned)(kb_ + wn * 64 + j * 16 + col);              \
          }                                                                         \
        }                                                                           \
      }                                                                             \
    }                                                                               \
  } while (0)

#define SAVEACC                                                                     \
  do {                                                                              \
    _Pragma("unroll") for (int i = 0; i < 4; ++i)                                   \
        _Pragma("unroll") for (int j = 0; j < 4; ++j) accH[i][j] = acc[i][j];       \
  } while (0)

#pragma unroll
  for (int nt = 0; nt < 7; ++nt) {
    ZEROACC;
#pragma unroll
    for (int ct = 0; ct < 8; ++ct) CHUNK(ct, true, nt * 8 + ct + 2, 2);
    TILE_SCORE(nt);
    if (nt == 0) {
      SAVEACC;
    } else {
      if (nt == 1) PUSH_DEFER;
      PUSH_CUR(nt);
    }
  }
  // nt = 7 epilogue: stop staging at chunk 63, then drain
  ZEROACC;
  CHUNK(0, true, 58, 2);
  CHUNK(1, true, 59, 2);
  CHUNK(2, true, 60, 2);
  CHUNK(3, true, 61, 2);
  CHUNK(4, true, 62, 2);
  CHUNK(5, true, 63, 2);
  CHUNK(6, false, 0, 0);
  CHUNK(7, false, 0, 3);
  TILE_SCORE(7);
  PUSH_CUR(7);

#undef STAGE_B
#undef CHUNK
#undef ZEROACC
#undef TILE_SCORE
#undef PUSH_CUR
#undef PUSH_DEFER
#undef SAVEACC
}

// ---------------------------------------------------------------------------
// Exact fp32 rescore of all pushed pairs (np chain, R4-verified machinery).
// One wave per pair; winner per q via packed atomicMin (ties -> min k).
// ---------------------------------------------------------------------------
__global__ __launch_bounds__(256) void exact_cand(const float* __restrict__ zT,
                                                  const float* __restrict__ cb,
                                                  const float* __restrict__ cbnorm,
                                                  const float* __restrict__ znorm,
                                                  const unsigned* __restrict__ pairs,
                                                  const int* __restrict__ paircount,
                                                  unsigned long long* __restrict__ packed) {
  const int cnt = min(*paircount, CAP_PAIRS);
  const int gw = (blockIdx.x * 256 + threadIdx.x) >> 6;
  const int nw = (gridDim.x * 256) >> 6;
  const int lane = threadIdx.x & 63;
  for (int p = gw; p < cnt; p += nw) {
    const unsigned qk = pairs[p];
    const int q = qk >> 13, k = qk & 8191;
    const float4 cv = ((const float4*)(cb + (size_t)k * FEAT))[lane];
    const float4 zv = ((const float4*)(zT + (size_t)q * FEAT))[lane];
    float d = __builtin_fmaf(zv.w, cv.w,
              __builtin_fmaf(zv.z, cv.z,
              __builtin_fmaf(zv.y, cv.y, __fmul_rn(zv.x, cv.x))));
#pragma unroll
    for (int dd = 1; dd < 64; dd <<= 1) d = __fadd_rn(d, __shfl_xor(d, dd, 64));
    const float s = __fadd_rn(__fadd_rn(__fmul_rn(-2.0f, d), znorm[q]), cbnorm[k]);
    if (lane == 0) {
      const unsigned long long key = ((unsigned long long)f2mono(s) << 32) | (unsigned)k;
      atomicMin(&packed[q], key);
    }
  }
}

// ---------------------------------------------------------------------------
// Gather: zq[b][c][hw] = cb[idx]; idx as float appended after zq.
// ---------------------------------------------------------------------------
__global__ __launch_bounds__(256) void vq_gather(const float* __restrict__ cb,
                                                 const unsigned long long* __restrict__ packed,
                                                 float* __restrict__ out) {
  const int q0 = blockIdx.x * 64;
  const int nl = threadIdx.x & 63;
  const int cg = threadIdx.x >> 6;
  const int q = q0 + nl;
  const int kq = (int)((unsigned)packed[q] & 8191u);
  const int b = q >> 10, hw = q & 1023;
  const float4* cb4 = (const float4*)cb;
#pragma unroll
  for (int t = 0; t < 16; ++t) {
    const int cc = cg + t * 4;
    const float4 v = cb4[kq * 64 + cc];
    const int base = b * (FEAT * 1024) + (cc * 4) * 1024 + hw;
    out[base] = v.x;
    out[base + 1024] = v.y;
    out[base + 2048] = v.z;
    out[base + 3072] = v.w;
  }
  if (threadIdx.x < 64) {
    const int qq = q0 + threadIdx.x;
    out[ZQ_ELEMS + qq] = (float)(int)((unsigned)packed[qq] & 8191u);
  }
}

extern "C" void kernel_launch(void* const* d_in, const int* in_sizes, int n_in,
                              void* d_out, int out_size, void* d_ws, size_t ws_size,
                              hipStream_t stream) {
  const float* z = (const float*)d_in[0];
  const float* cb = (const float*)d_in[1];
  char* w = (char*)d_ws;
  // ws layout (~29.3 MiB)
  char* At = w;                                            // 8 MB
  char* Bt = w + 8388608;                                  // 4 MB
  float* zT = (float*)(w + 12582912);                      // 16 MB
  float* cbnorm = (float*)(w + 29360128);                  // 32 KB
  float* znorm = (float*)(w + 29392896);                   // 64 KB
  unsigned* gmin = (unsigned*)(w + 29458432);              // 64 KB
  int* paircount = (int*)(w + 29523968);                   // 256 B
  unsigned* pairs = (unsigned*)(w + 29524224);             // 1 MB (256K pairs)
  unsigned long long* packed = (unsigned long long*)(w + 30572800);  // 128 KB

  hipMemsetAsync(paircount, 0, 256, stream);
  hipMemsetAsync(gmin, 0xFF, NQ * sizeof(unsigned), stream);
  hipMemsetAsync(packed, 0xFF, NQ * sizeof(unsigned long long), stream);
  norms_kernel<<<(CODES + NQ) / 16, 256, 0, stream>>>(cb, z, cbnorm, znorm);
  convA<<<1024, 256, 0, stream>>>(z, At, zT);
  convB<<<512, 256, 0, stream>>>(cb, Bt);
  gemm_fused<<<(NQ / 128) * NSLICE, 256, 0, stream>>>(At, Bt, cbnorm, gmin, pairs, paircount);
  exact_cand<<<512, 256, 0, stream>>>(zT, cb, cbnorm, znorm, pairs, paircount, packed);
  vq_gather<<<NQ / 64, 256, 0, stream>>>(cb, packed, (float*)d_out);
}

// Round 4
// 535.773 us; speedup vs baseline: 1.4074x; 1.4074x over previous
//
#include <hip/hip_runtime.h>
#include <stdint.h>

#define FEAT 256
#define CODES 8192
#define NQ 16384                 // 16*32*32
#define ZQ_ELEMS (NQ * FEAT)
#define MARGIN 2e-3f             // = 2e bound on fp16 score error (R4-validated)
#define NSLICE 8
#define CAP_PAIRS (1 << 17)      // 128K (expected ~18K)
#define KSC (-0.0078125f)        // descale: acc * -2/256

typedef _Float16 f16x8 __attribute__((ext_vector_type(8)));
typedef float f32x4 __attribute__((ext_vector_type(4)));

__device__ __forceinline__ void async_lds16(void* lds, const void* g) {
  __builtin_amdgcn_global_load_lds(
      (const __attribute__((address_space(1))) void*)(uintptr_t)(g),
      (__attribute__((address_space(3))) void*)(uint32_t)(uintptr_t)(lds),
      16, 0, 0);
}

// monotone float<->uint order transform
__device__ __forceinline__ unsigned f2mono(float v) {
  unsigned u = __float_as_uint(v);
  return (u & 0x80000000u) ? ~u : (u | 0x80000000u);
}
__device__ __forceinline__ float mono2f(unsigned t) {
  unsigned u = (t & 0x80000000u) ? (t & 0x7fffffffu) : ~t;
  return __uint_as_float(u);
}

// ---------------------------------------------------------------------------
// numpy pairwise sum-of-squares replication (verified R1-R4, absmax 0).
// ---------------------------------------------------------------------------
template <int STRIDE>
__device__ __forceinline__ float pairwise256_sq(const float* __restrict__ base, int lane16) {
  const int h = lane16 >> 3, j = lane16 & 7;
  const float* p = base + (h * 128 + j) * STRIDE;
  float x = p[0];
  float r = __fmul_rn(x, x);
#pragma unroll
  for (int i = 1; i < 16; ++i) {
    float y = p[i * 8 * STRIDE];
    r = __fadd_rn(r, __fmul_rn(y, y));
  }
  r = __fadd_rn(r, __shfl_xor(r, 1, 64));
  r = __fadd_rn(r, __shfl_xor(r, 2, 64));
  r = __fadd_rn(r, __shfl_xor(r, 4, 64));
  float other = __shfl_xor(r, 8, 64);
  float lo = (h == 0) ? r : other;
  float hi = (h == 0) ? other : r;
  return __fadd_rn(lo, hi);
}

__global__ __launch_bounds__(256) void norms_kernel(const float* __restrict__ cb,
                                                    const float* __restrict__ z,
                                                    float* __restrict__ cbnorm,
                                                    float* __restrict__ znorm) {
  const int g = (blockIdx.x * 256 + threadIdx.x) >> 4;
  const int lane16 = threadIdx.x & 15;
  if (g < CODES) {
    float v = pairwise256_sq<1>(cb + g * FEAT, lane16);
    if (lane16 == 0) cbnorm[g] = v;
  } else {
    const int q = g - CODES;
    const int b = q >> 10, hw = q & 1023;
    float v = pairwise256_sq<1024>(z + b * (FEAT * 1024) + hw, lane16);
    if (lane16 == 0) znorm[q] = v;
  }
}

// ---------------------------------------------------------------------------
// convA: z fp32 -> fp16 tiles [mt][ct][r128][c32] + fp32 transpose zT[q][c]
// ---------------------------------------------------------------------------
__global__ __launch_bounds__(256) void convA(const float* __restrict__ z,
                                             char* __restrict__ At, float* __restrict__ zT) {
  __shared__ _Float16 T[128 * 40];
  __shared__ float Tf[128 * 36];
  const int t = threadIdx.x;
  const int mt = blockIdx.x >> 3, ct = blockIdx.x & 7;
  const int q0 = mt * 128, bb = q0 >> 10, hw0 = q0 & 1023;
  const int c0 = ct * 32;
#pragma unroll
  for (int it = 0; it < 16; ++it) {
    const int cc = it * 2 + (t >> 7);
    const int qi = t & 127;
    float v = z[bb * (FEAT * 1024) + (c0 + cc) * 1024 + hw0 + qi];
    T[qi * 40 + cc] = (_Float16)v;
    Tf[qi * 36 + cc] = v;
  }
  __syncthreads();
  const int r = t >> 1, h = t & 1;
  {
    float4 a = *(const float4*)&T[r * 40 + h * 16];
    float4 b = *(const float4*)&T[r * 40 + h * 16 + 8];
    char* dst = At + (size_t)(mt * 8 + ct) * 8192 + t * 32;
    *(float4*)dst = a;
    *(float4*)(dst + 16) = b;
  }
  float* zrow = zT + (size_t)(q0 + r) * FEAT + c0 + h * 16;
#pragma unroll
  for (int e = 0; e < 4; ++e)
    *(float4*)(zrow + e * 4) = *(const float4*)&Tf[r * 36 + h * 16 + e * 4];
}

// ---------------------------------------------------------------------------
// convB: cb fp32 -> fp16 FRAGMENT-LINEAR layout, scaled by 256.
// For chunk cg = nt*8+ct, wn in {0,1}, j in [0,4): a contiguous 1KB block of
// 64 lanes x 16B where lane l holds
//   f16(cb[nt*128 + wn*64 + j*16 + (l&15)][ct*32 + (l>>4)*8 .. +8] * 256)
// Verified absmax 0 in R1/R2.
// ---------------------------------------------------------------------------
__global__ __launch_bounds__(256) void convB(const float* __restrict__ cb, char* __restrict__ Bt) {
  const int T = blockIdx.x * 256 + threadIdx.x;   // [0, 131072)
  const int K = T >> 4, part = T & 15;            // K: code row; part: 16-float chunk
  const float* src = cb + (size_t)K * FEAT + part * 16;
  const int nt = K >> 7, rem = K & 127;
  const int wn = rem >> 6, j = (rem >> 4) & 3, llo = rem & 15;
#pragma unroll
  for (int g = 0; g < 2; ++g) {
    const int c0 = part * 16 + g * 8;
    const int ct = c0 >> 5, lhi = (c0 >> 3) & 3;
    const int cg = nt * 8 + ct;
    f16x8 o;
#pragma unroll
    for (int e = 0; e < 8; ++e) o[e] = (_Float16)(src[g * 8 + e] * 256.0f);
    const size_t s = ((size_t)((cg * 2 + wn) * 4 + j) << 6) + (size_t)(lhi * 16 + llo);
    *(f16x8*)(Bt + s * 16) = o;
  }
}

// ---------------------------------------------------------------------------
// Shared GEMM body, STREAMING BOTH OPERANDS. A and B each flow through an
// 8 KB x2 double-buffered LDS ring (32 KB total -> 5 blocks/CU by LDS,
// vs 2 with the 64 KB resident A tile). A-chunk for absolute chunk c is
// (c & 7), so A re-stages the same 8 chunks per nt-tile (extra reads come
// from L2/L3; At is 8 MB, L3-resident). Counted vmcnt(4) waits (4 loads per
// stage: 2 A + 2 B), depth-2, never drained in the main loop.
// PASS=0: per-row running min -> atomicMin gmin[q] (monotone u32).
// PASS=1: push (q<<13|k) for every score <= thr[q] = gmin[q] + MARGIN,
//         with exact row-min early-out.
// ---------------------------------------------------------------------------
template <int PASS>
__device__ __forceinline__ void gemm_body(const char* __restrict__ At,
                                          const char* __restrict__ Bt,
                                          const float* __restrict__ cbnorm,
                                          unsigned* __restrict__ gmin,
                                          unsigned* __restrict__ pairs,
                                          int* __restrict__ paircount) {
  __shared__ __align__(16) char Ar[16384];   // 2 x 8KB ring
  __shared__ __align__(16) char Br[16384];   // 2 x 8KB ring

  const int tid = threadIdx.x;
  const int slice = blockIdx.x & 7, mt = blockIdx.x >> 3;
  const int wave = tid >> 6, lane = tid & 63;
  const int wm = wave >> 1, wn = wave & 1;
  const int col = lane & 15, quad = lane >> 4;

  const int srow = wave * 32 + (lane >> 2);  // A staging row within 32-row group
  const int ss = lane & 3;
  const char* Abase = At + (size_t)(mt * 8) * 8192;
  const char* Bslice = Bt + (size_t)slice * 524288;

#define STAGE_A(SLOT, CT8)                                                          \
  do {                                                                              \
    _Pragma("unroll") for (int i_ = 0; i_ < 2; ++i_) {                              \
      const int r_ = srow + i_ * 16;                                                \
      const int cs_ = ss ^ ((r_ >> 1) & 3);                                         \
      async_lds16(Ar + (SLOT) * 8192 + wave * 2048 + i_ * 1024,                     \
                  Abase + (size_t)(CT8) * 8192 + r_ * 64 + cs_ * 16);               \
    }                                                                               \
  } while (0)

#define STAGE_B(SLOT, CIDX)                                                         \
  do {                                                                              \
    const char* gs_ = Bslice + ((size_t)(CIDX) << 13) + wave * 2048 + lane * 16;    \
    async_lds16(Br + (SLOT) * 8192 + wave * 2048, gs_);                             \
    async_lds16(Br + (SLOT) * 8192 + wave * 2048 + 1024, gs_ + 1024);               \
  } while (0)

  // prime the rings: chunks 0 and 1
  STAGE_A(0, 0);
  STAGE_B(0, 0);
  STAGE_A(1, 1);
  STAGE_B(1, 1);

  int aoff[4];
#pragma unroll
  for (int i = 0; i < 4; ++i) {
    const int m = wm * 64 + i * 16 + col;
    aoff[i] = m * 64 + ((quad ^ ((m >> 1) & 3)) << 4);   // chunk-local offset
  }

  int qrow[16];
#pragma unroll
  for (int row = 0; row < 16; ++row)
    qrow[row] = mt * 128 + wm * 64 + (row >> 2) * 16 + quad * 4 + (row & 3);

  float vmin[16], thr[16];
#pragma unroll
  for (int row = 0; row < 16; ++row) vmin[row] = 3.4e38f;
  if (PASS == 1) {
    // issued before __syncthreads so the vmcnt drain covers them
#pragma unroll
    for (int row = 0; row < 16; ++row) thr[row] = mono2f(gmin[qrow[row]]) + MARGIN;
  }

  f32x4 acc[4][4];

  __syncthreads();  // full drain once: chunks 0,1 of both rings landed

  // Per-chunk step; CT in [0,8) compile-time (ring slot = CT&1, A src = (CT+2)&7).
  // WMODE 4: s_waitcnt vmcnt(4) -- the 4 newest outstanding VMEM ops are this
  // chunk's stage(c+2); everything older (incl. stage(c+1)) is complete.
  // 0: drain. 3: no wait (final chunk).
#define CHUNK(CT, STG, CNEXT, WMODE)                                                \
  do {                                                                              \
    const int P_ = (CT) & 1;                                                        \
    f16x8 bf_[4], af_[4];                                                           \
    _Pragma("unroll") for (int j = 0; j < 4; ++j)                                   \
        bf_[j] = *(const f16x8*)(Br + P_ * 8192 + wn * 4096 + j * 1024 + lane * 16);\
    _Pragma("unroll") for (int i = 0; i < 4; ++i)                                   \
        af_[i] = *(const f16x8*)(Ar + P_ * 8192 + aoff[i]);                         \
    asm volatile("s_waitcnt lgkmcnt(0)" ::: "memory");                              \
    __builtin_amdgcn_sched_barrier(0);                                              \
    __builtin_amdgcn_s_barrier(); /* all waves done reading slot P_ */              \
    if (STG) {                                                                      \
      STAGE_A(P_, ((CT) + 2) & 7);                                                  \
      STAGE_B(P_, CNEXT);                                                           \
      __builtin_amdgcn_sched_barrier(0); /* keep loads issued before MFMA */        \
    }                                                                               \
    _Pragma("unroll") for (int i = 0; i < 4; ++i)                                   \
        _Pragma("unroll") for (int j = 0; j < 4; ++j)                               \
            acc[i][j] = __builtin_amdgcn_mfma_f32_16x16x32_f16(af_[i], bf_[j],      \
                                                               acc[i][j], 0, 0, 0); \
    if ((WMODE) == 4) {                                                             \
      asm volatile("s_waitcnt vmcnt(4)" ::: "memory");                              \
      __builtin_amdgcn_sched_barrier(0);                                            \
    }                                                                               \
    if ((WMODE) == 0) {                                                             \
      asm volatile("s_waitcnt vmcnt(0)" ::: "memory");                              \
      __builtin_amdgcn_sched_barrier(0);                                            \
    }                                                                               \
    __builtin_amdgcn_s_barrier(); /* next slot staged for all waves */              \
  } while (0)

#define ZEROACC                                                                     \
  do {                                                                              \
    _Pragma("unroll") for (int i = 0; i < 4; ++i)                                   \
        _Pragma("unroll") for (int j = 0; j < 4; ++j)                               \
            acc[i][j] = (f32x4){0.f, 0.f, 0.f, 0.f};                                \
  } while (0)

#define SCORING(NT)                                                                 \
  do {                                                                              \
    const int k0_ = (slice * 8 + (NT)) * 128;                                       \
    float cn_[4];                                                                   \
    _Pragma("unroll") for (int j = 0; j < 4; ++j)                                   \
        cn_[j] = cbnorm[k0_ + wn * 64 + j * 16 + col];                              \
    _Pragma("unroll") for (int i = 0; i < 4; ++i)                                   \
        _Pragma("unroll") for (int r = 0; r < 4; ++r) {                             \
      const int row_ = i * 4 + r;                                                   \
      const float s0_ = __builtin_fmaf(acc[i][0][r], KSC, cn_[0]);                  \
      const float s1_ = __builtin_fmaf(acc[i][1][r], KSC, cn_[1]);                  \
      const float s2_ = __builtin_fmaf(acc[i][2][r], KSC, cn_[2]);                  \
      const float s3_ = __builtin_fmaf(acc[i][3][r], KSC, cn_[3]);                  \
      const float rm_ = fminf(fminf(s0_, s1_), fminf(s2_, s3_));                    \
      if (PASS == 0) {                                                              \
        vmin[row_] = fminf(vmin[row_], rm_);                                        \
      } else if (rm_ <= thr[row_]) { /* exact early-out: min_j > thr => none */     \
        const float sv_[4] = {s0_, s1_, s2_, s3_};                                  \
        _Pragma("unroll") for (int j = 0; j < 4; ++j) {                             \
          if (sv_[j] <= thr[row_]) {                                                \
            const int slot_ = atomicAdd(paircount, 1);                              \
            if (slot_ < CAP_PAIRS)                                                  \
              pairs[slot_] = ((unsigned)qrow[row_] << 13) |                         \
                             (unsigned)(k0_ + wn * 64 + j * 16 + col);              \
          }                                                                         \
        }                                                                           \
      }                                                                             \
    }                                                                               \
  } while (0)

  for (int nt = 0; nt < 7; ++nt) {
    ZEROACC;
#pragma unroll
    for (int ct = 0; ct < 8; ++ct) CHUNK(ct, true, nt * 8 + ct + 2, 4);
    SCORING(nt);
  }
  // nt = 7 epilogue: stop staging at chunk 63, then drain
  ZEROACC;
  CHUNK(0, true, 58, 4);
  CHUNK(1, true, 59, 4);
  CHUNK(2, true, 60, 4);
  CHUNK(3, true, 61, 4);
  CHUNK(4, true, 62, 4);
  CHUNK(5, true, 63, 4);
  CHUNK(6, false, 0, 0);
  CHUNK(7, false, 0, 3);
  SCORING(7);

#undef STAGE_A
#undef STAGE_B
#undef CHUNK
#undef ZEROACC
#undef SCORING

  if (PASS == 0) {
    // cross-col min (value only), then atomicMin per row
#pragma unroll
    for (int row = 0; row < 16; ++row) {
      float v = vmin[row];
      v = fminf(v, __shfl_xor(v, 1, 64));
      v = fminf(v, __shfl_xor(v, 2, 64));
      v = fminf(v, __shfl_xor(v, 4, 64));
      v = fminf(v, __shfl_xor(v, 8, 64));
      if (col == 0) atomicMin(&gmin[qrow[row]], f2mono(v));
    }
  }
}

__global__ __launch_bounds__(256, 4) void gemm_pass1(const char* __restrict__ At,
                                                     const char* __restrict__ Bt,
                                                     const float* __restrict__ cbnorm,
                                                     unsigned* __restrict__ gmin) {
  gemm_body<0>(At, Bt, cbnorm, gmin, nullptr, nullptr);
}

__global__ __launch_bounds__(256, 4) void gemm_pass2(const char* __restrict__ At,
                                                     const char* __restrict__ Bt,
                                                     const float* __restrict__ cbnorm,
                                                     unsigned* __restrict__ gmin,
                                                     unsigned* __restrict__ pairs,
                                                     int* __restrict__ paircount) {
  gemm_body<1>(At, Bt, cbnorm, gmin, pairs, paircount);
}

// ---------------------------------------------------------------------------
// Exact fp32 rescore of all pushed pairs (np chain, R4-verified machinery).
// One wave per pair; winner per q via packed atomicMin (ties -> min k).
// ---------------------------------------------------------------------------
__global__ __launch_bounds__(256) void exact_cand(const float* __restrict__ zT,
                                                  const float* __restrict__ cb,
                                                  const float* __restrict__ cbnorm,
                                                  const float* __restrict__ znorm,
                                                  const unsigned* __restrict__ pairs,
                                                  const int* __restrict__ paircount,
                                                  unsigned long long* __restrict__ packed) {
  const int cnt = min(*paircount, CAP_PAIRS);
  const int gw = (blockIdx.x * 256 + threadIdx.x) >> 6;
  const int nw = (gridDim.x * 256) >> 6;
  const int lane = threadIdx.x & 63;
  for (int p = gw; p < cnt; p += nw) {
    const unsigned qk = pairs[p];
    const int q = qk >> 13, k = qk & 8191;
    const float4 cv = ((const float4*)(cb + (size_t)k * FEAT))[lane];
    const float4 zv = ((const float4*)(zT + (size_t)q * FEAT))[lane];
    float d = __builtin_fmaf(zv.w, cv.w,
              __builtin_fmaf(zv.z, cv.z,
              __builtin_fmaf(zv.y, cv.y, __fmul_rn(zv.x, cv.x))));
#pragma unroll
    for (int dd = 1; dd < 64; dd <<= 1) d = __fadd_rn(d, __shfl_xor(d, dd, 64));
    const float s = __fadd_rn(__fadd_rn(__fmul_rn(-2.0f, d), znorm[q]), cbnorm[k]);
    if (lane == 0) {
      const unsigned long long key = ((unsigned long long)f2mono(s) << 32) | (unsigned)k;
      atomicMin(&packed[q], key);
    }
  }
}

// ---------------------------------------------------------------------------
// Gather: zq[b][c][hw] = cb[idx]; idx as float appended after zq.
// ---------------------------------------------------------------------------
__global__ __launch_bounds__(256) void vq_gather(const float* __restrict__ cb,
                                                 const unsigned long long* __restrict__ packed,
                                                 float* __restrict__ out) {
  const int q0 = blockIdx.x * 64;
  const int nl = threadIdx.x & 63;
  const int cg = threadIdx.x >> 6;
  const int q = q0 + nl;
  const int kq = (int)((unsigned)packed[q] & 8191u);
  const int b = q >> 10, hw = q & 1023;
  const float4* cb4 = (const float4*)cb;
#pragma unroll
  for (int t = 0; t < 16; ++t) {
    const int cc = cg + t * 4;
    const float4 v = cb4[kq * 64 + cc];
    const int base = b * (FEAT * 1024) + (cc * 4) * 1024 + hw;
    out[base] = v.x;
    out[base + 1024] = v.y;
    out[base + 2048] = v.z;
    out[base + 3072] = v.w;
  }
  if (threadIdx.x < 64) {
    const int qq = q0 + threadIdx.x;
    out[ZQ_ELEMS + qq] = (float)(int)((unsigned)packed[qq] & 8191u);
  }
}

extern "C" void kernel_launch(void* const* d_in, const int* in_sizes, int n_in,
                              void* d_out, int out_size, void* d_ws, size_t ws_size,
                              hipStream_t stream) {
  const float* z = (const float*)d_in[0];
  const float* cb = (const float*)d_in[1];
  char* w = (char*)d_ws;
  // ws layout (~29.2 MB)
  char* At = w;                                            // 8 MB
  char* Bt = w + 8388608;                                  // 4 MB
  float* zT = (float*)(w + 12582912);                      // 16 MB
  float* cbnorm = (float*)(w + 29360128);                  // 32 KB
  float* znorm = (float*)(w + 29392896);                   // 64 KB
  unsigned* gmin = (unsigned*)(w + 29458432);              // 64 KB
  int* paircount = (int*)(w + 29523968);                   // 256 B
  unsigned* pairs = (unsigned*)(w + 29524224);             // 512 KB
  unsigned long long* packed = (unsigned long long*)(w + 30048512);  // 128 KB

  hipMemsetAsync(paircount, 0, 256, stream);
  hipMemsetAsync(gmin, 0xFF, NQ * sizeof(unsigned), stream);
  hipMemsetAsync(packed, 0xFF, NQ * sizeof(unsigned long long), stream);
  norms_kernel<<<(CODES + NQ) / 16, 256, 0, stream>>>(cb, z, cbnorm, znorm);
  convA<<<1024, 256, 0, stream>>>(z, At, zT);
  convB<<<512, 256, 0, stream>>>(cb, Bt);
  gemm_pass1<<<(NQ / 128) * NSLICE, 256, 0, stream>>>(At, Bt, cbnorm, gmin);
  gemm_pass2<<<(NQ / 128) * NSLICE, 256, 0, stream>>>(At, Bt, cbnorm, gmin, pairs, paircount);
  exact_cand<<<256, 256, 0, stream>>>(zT, cb, cbnorm, znorm, pairs, paircount, packed);
  vq_gather<<<NQ / 64, 256, 0, stream>>>(cb, packed, (float*)d_out);
}

// Round 5
// 395.205 us; speedup vs baseline: 1.9080x; 1.3557x over previous
//
#include <hip/hip_runtime.h>
#include <stdint.h>

#define FEAT 256
#define CODES 8192
#define NQ 16384                 // 16*32*32
#define ZQ_ELEMS (NQ * FEAT)
#define MARGIN 2e-3f             // = 2e bound on fp16 score error (R4-validated)
#define F16STORE_ERR 1.0e-3f     // RTN fp16 storage slack for |s|<2
#define NSLICE 8
#define CAP_PAIRS (1 << 17)      // 128K (expected ~27K with widened threshold)
#define KSC (-0.0078125f)        // descale: acc * -2/256
#define SCORES_OFF 33554432ull   // ws offset of packed score matrix
#define SCORES_BYTES 268435456ull

typedef _Float16 f16x8 __attribute__((ext_vector_type(8)));
typedef float f32x4 __attribute__((ext_vector_type(4)));

__device__ __forceinline__ void async_lds16(void* lds, const void* g) {
  __builtin_amdgcn_global_load_lds(
      (const __attribute__((address_space(1))) void*)(uintptr_t)(g),
      (__attribute__((address_space(3))) void*)(uint32_t)(uintptr_t)(lds),
      16, 0, 0);
}

// monotone float<->uint order transform
__device__ __forceinline__ unsigned f2mono(float v) {
  unsigned u = __float_as_uint(v);
  return (u & 0x80000000u) ? ~u : (u | 0x80000000u);
}
__device__ __forceinline__ float mono2f(unsigned t) {
  unsigned u = (t & 0x80000000u) ? (t & 0x7fffffffu) : ~t;
  return __uint_as_float(u);
}
__device__ __forceinline__ unsigned pack_f16x2(float a, float b) {
  unsigned short ha = __builtin_bit_cast(unsigned short, (_Float16)a);
  unsigned short hb = __builtin_bit_cast(unsigned short, (_Float16)b);
  return (unsigned)ha | ((unsigned)hb << 16);
}

// ---------------------------------------------------------------------------
// numpy pairwise sum-of-squares replication (verified R1-R4, absmax 0).
// ---------------------------------------------------------------------------
template <int STRIDE>
__device__ __forceinline__ float pairwise256_sq(const float* __restrict__ base, int lane16) {
  const int h = lane16 >> 3, j = lane16 & 7;
  const float* p = base + (h * 128 + j) * STRIDE;
  float x = p[0];
  float r = __fmul_rn(x, x);
#pragma unroll
  for (int i = 1; i < 16; ++i) {
    float y = p[i * 8 * STRIDE];
    r = __fadd_rn(r, __fmul_rn(y, y));
  }
  r = __fadd_rn(r, __shfl_xor(r, 1, 64));
  r = __fadd_rn(r, __shfl_xor(r, 2, 64));
  r = __fadd_rn(r, __shfl_xor(r, 4, 64));
  float other = __shfl_xor(r, 8, 64);
  float lo = (h == 0) ? r : other;
  float hi = (h == 0) ? other : r;
  return __fadd_rn(lo, hi);
}

__global__ __launch_bounds__(256) void norms_kernel(const float* __restrict__ cb,
                                                    const float* __restrict__ z,
                                                    float* __restrict__ cbnorm,
                                                    float* __restrict__ znorm) {
  const int g = (blockIdx.x * 256 + threadIdx.x) >> 4;
  const int lane16 = threadIdx.x & 15;
  if (g < CODES) {
    float v = pairwise256_sq<1>(cb + g * FEAT, lane16);
    if (lane16 == 0) cbnorm[g] = v;
  } else {
    const int q = g - CODES;
    const int b = q >> 10, hw = q & 1023;
    float v = pairwise256_sq<1024>(z + b * (FEAT * 1024) + hw, lane16);
    if (lane16 == 0) znorm[q] = v;
  }
}

// ---------------------------------------------------------------------------
// convA: z fp32 -> fp16 tiles [mt][ct][r128][c32] + fp32 transpose zT[q][c]
// ---------------------------------------------------------------------------
__global__ __launch_bounds__(256) void convA(const float* __restrict__ z,
                                             char* __restrict__ At, float* __restrict__ zT) {
  __shared__ _Float16 T[128 * 40];
  __shared__ float Tf[128 * 36];
  const int t = threadIdx.x;
  const int mt = blockIdx.x >> 3, ct = blockIdx.x & 7;
  const int q0 = mt * 128, bb = q0 >> 10, hw0 = q0 & 1023;
  const int c0 = ct * 32;
#pragma unroll
  for (int it = 0; it < 16; ++it) {
    const int cc = it * 2 + (t >> 7);
    const int qi = t & 127;
    float v = z[bb * (FEAT * 1024) + (c0 + cc) * 1024 + hw0 + qi];
    T[qi * 40 + cc] = (_Float16)v;
    Tf[qi * 36 + cc] = v;
  }
  __syncthreads();
  const int r = t >> 1, h = t & 1;
  {
    float4 a = *(const float4*)&T[r * 40 + h * 16];
    float4 b = *(const float4*)&T[r * 40 + h * 16 + 8];
    char* dst = At + (size_t)(mt * 8 + ct) * 8192 + t * 32;
    *(float4*)dst = a;
    *(float4*)(dst + 16) = b;
  }
  float* zrow = zT + (size_t)(q0 + r) * FEAT + c0 + h * 16;
#pragma unroll
  for (int e = 0; e < 4; ++e)
    *(float4*)(zrow + e * 4) = *(const float4*)&Tf[r * 36 + h * 16 + e * 4];
}

// ---------------------------------------------------------------------------
// convB: cb fp32 -> fp16 FRAGMENT-LINEAR layout, scaled by 256.
// For chunk cg = nt*8+ct, wn in {0,1}, j in [0,4): a contiguous 1KB block of
// 64 lanes x 16B where lane l holds
//   f16(cb[nt*128 + wn*64 + j*16 + (l&15)][ct*32 + (l>>4)*8 .. +8] * 256)
// Verified absmax 0 in R1/R2/R4.
// ---------------------------------------------------------------------------
__global__ __launch_bounds__(256) void convB(const float* __restrict__ cb, char* __restrict__ Bt) {
  const int T = blockIdx.x * 256 + threadIdx.x;   // [0, 131072)
  const int K = T >> 4, part = T & 15;            // K: code row; part: 16-float chunk
  const float* src = cb + (size_t)K * FEAT + part * 16;
  const int nt = K >> 7, rem = K & 127;
  const int wn = rem >> 6, j = (rem >> 4) & 3, llo = rem & 15;
#pragma unroll
  for (int g = 0; g < 2; ++g) {
    const int c0 = part * 16 + g * 8;
    const int ct = c0 >> 5, lhi = (c0 >> 3) & 3;
    const int cg = nt * 8 + ct;
    f16x8 o;
#pragma unroll
    for (int e = 0; e < 8; ++e) o[e] = (_Float16)(src[g * 8 + e] * 256.0f);
    const size_t s = ((size_t)((cg * 2 + wn) * 4 + j) << 6) + (size_t)(lhi * 16 + llo);
    *(f16x8*)(Bt + s * 16) = o;
  }
}

// ---------------------------------------------------------------------------
// Shared GEMM body, R2-proven structure: A-tile (64 KB, all K) resident in
// LDS; B chunks (8 KB) double-buffered via global_load_lds, counted vmcnt(2)
// waits, raw s_barriers, sched_barrier(0) fences.
// PASS=0: per-row running min -> atomicMin gmin[q].
// PASS=1: (fallback pass2) push (q<<13|k) for score <= gmin[q]+MARGIN.
// PASS=2: PASS0 + store all scores packed fp16x2 in fragment order.
// ---------------------------------------------------------------------------
template <int PASS>
__device__ __forceinline__ void gemm_body(const char* __restrict__ At,
                                          const char* __restrict__ Bt,
                                          const float* __restrict__ cbnorm,
                                          unsigned* __restrict__ gmin,
                                          unsigned* __restrict__ pairs,
                                          int* __restrict__ paircount,
                                          unsigned* __restrict__ scores) {
  __shared__ __align__(16) char Af[65536];
  __shared__ __align__(16) char Bs0[8192];
  __shared__ __align__(16) char Bs1[8192];

  const int tid = threadIdx.x;
  const int slice = blockIdx.x & 7, mt = blockIdx.x >> 3;
  const int wave = tid >> 6, lane = tid & 63;
  const int wm = wave >> 1, wn = wave & 1;
  const int col = lane & 15, quad = lane >> 4;

  const int srow = wave * 32 + (lane >> 2);  // A staging row within 32-row group
  const int ss = lane & 3;
  const char* Abase = At + (size_t)(mt * 8) * 8192;
  const char* Bslice = Bt + (size_t)slice * 524288;

  // stage entire A tile (8 ct-chunks) into LDS, swizzled slots
#pragma unroll
  for (int ct = 0; ct < 8; ++ct) {
#pragma unroll
    for (int i = 0; i < 2; ++i) {
      const int r = srow + i * 16;
      const int cs = ss ^ ((r >> 1) & 3);
      async_lds16(Af + ct * 8192 + wave * 2048 + i * 1024,
                  Abase + (size_t)ct * 8192 + r * 64 + cs * 16);
    }
  }

#define STAGE_B(BUF, CIDX)                                                          \
  do {                                                                              \
    const char* gs_ = Bslice + ((size_t)(CIDX) << 13) + wave * 2048 + lane * 16;    \
    async_lds16((BUF) + wave * 2048, gs_);                                          \
    async_lds16((BUF) + wave * 2048 + 1024, gs_ + 1024);                            \
  } while (0)

  // prime double-buffer: chunks 0 and 1
  STAGE_B(Bs0, 0);
  STAGE_B(Bs1, 1);

  int aoff[4];
#pragma unroll
  for (int i = 0; i < 4; ++i) {
    const int m = wm * 64 + i * 16 + col;
    aoff[i] = m * 64 + ((quad ^ ((m >> 1) & 3)) << 4);
  }

  int qrow[16];
#pragma unroll
  for (int row = 0; row < 16; ++row)
    qrow[row] = mt * 128 + wm * 64 + (row >> 2) * 16 + quad * 4 + (row & 3);

  float vmin[16], thr[16];
#pragma unroll
  for (int row = 0; row < 16; ++row) vmin[row] = 3.4e38f;
  if (PASS == 1) {
#pragma unroll
    for (int row = 0; row < 16; ++row) thr[row] = mono2f(gmin[qrow[row]]) + MARGIN;
  }

  f32x4 acc[4][4];

  __syncthreads();  // full drain once: A tile + B chunks 0,1 landed

  // Per-chunk step. WMODE 2: s_waitcnt vmcnt(2) -- the 2 newest outstanding
  // VMEM ops are this chunk's stage(c+2); everything older (incl. stage(c+1)
  // and any score stores) is complete. 0: drain. 3: no wait (final chunk).
#define CHUNK(CT, STG, CNEXT, WMODE)                                                \
  do {                                                                              \
    char* Bcur_ = ((CT) & 1) ? Bs1 : Bs0;                                           \
    f16x8 bf_[4], af_[4];                                                           \
    _Pragma("unroll") for (int j = 0; j < 4; ++j)                                   \
        bf_[j] = *(const f16x8*)(Bcur_ + wn * 4096 + j * 1024 + lane * 16);         \
    _Pragma("unroll") for (int i = 0; i < 4; ++i)                                   \
        af_[i] = *(const f16x8*)(Af + (CT) * 8192 + aoff[i]);                       \
    asm volatile("s_waitcnt lgkmcnt(0)" ::: "memory");                              \
    __builtin_amdgcn_sched_barrier(0);                                              \
    __builtin_amdgcn_s_barrier(); /* all waves done reading Bcur_ */                \
    if (STG) {                                                                      \
      STAGE_B(Bcur_, CNEXT);                                                        \
      __builtin_amdgcn_sched_barrier(0); /* keep loads issued before MFMA */        \
    }                                                                               \
    _Pragma("unroll") for (int i = 0; i < 4; ++i)                                   \
        _Pragma("unroll") for (int j = 0; j < 4; ++j)                               \
            acc[i][j] = __builtin_amdgcn_mfma_f32_16x16x32_f16(af_[i], bf_[j],      \
                                                               acc[i][j], 0, 0, 0); \
    if ((WMODE) == 2) {                                                             \
      asm volatile("s_waitcnt vmcnt(2)" ::: "memory");                              \
      __builtin_amdgcn_sched_barrier(0);                                            \
    }                                                                               \
    if ((WMODE) == 0) {                                                             \
      asm volatile("s_waitcnt vmcnt(0)" ::: "memory");                              \
      __builtin_amdgcn_sched_barrier(0);                                            \
    }                                                                               \
    __builtin_amdgcn_s_barrier(); /* next buffer staged for all waves */            \
  } while (0)

#define ZEROACC                                                                     \
  do {                                                                              \
    _Pragma("unroll") for (int i = 0; i < 4; ++i)                                   \
        _Pragma("unroll") for (int j = 0; j < 4; ++j)                               \
            acc[i][j] = (f32x4){0.f, 0.f, 0.f, 0.f};                                \
  } while (0)

#define SCORING(NT)                                                                 \
  do {                                                                              \
    const int k0_ = (slice * 8 + (NT)) * 128;                                       \
    float cn_[4];                                                                   \
    _Pragma("unroll") for (int j = 0; j < 4; ++j)                                   \
        cn_[j] = cbnorm[k0_ + wn * 64 + j * 16 + col];                              \
    unsigned* sb_ = (PASS == 2)                                                     \
        ? scores + ((((unsigned)blockIdx.x * 8u + (unsigned)(NT)) * 4u +            \
                     (unsigned)wave) * 32u) * 64u + (unsigned)lane                  \
        : nullptr;                                                                  \
    _Pragma("unroll") for (int i = 0; i < 4; ++i)                                   \
        _Pragma("unroll") for (int r = 0; r < 4; ++r) {                             \
      const int row_ = i * 4 + r;                                                   \
      const float s0_ = __builtin_fmaf(acc[i][0][r], KSC, cn_[0]);                  \
      const float s1_ = __builtin_fmaf(acc[i][1][r], KSC, cn_[1]);                  \
      const float s2_ = __builtin_fmaf(acc[i][2][r], KSC, cn_[2]);                  \
      const float s3_ = __builtin_fmaf(acc[i][3][r], KSC, cn_[3]);                  \
      const float rm_ = fminf(fminf(s0_, s1_), fminf(s2_, s3_));                    \
      if (PASS != 1) {                                                              \
        vmin[row_] = fminf(vmin[row_], rm_);                                        \
        if (PASS == 2) {                                                            \
          sb_[(unsigned)(((i * 4 + r) * 2 + 0) * 64)] = pack_f16x2(s0_, s1_);       \
          sb_[(unsigned)(((i * 4 + r) * 2 + 1) * 64)] = pack_f16x2(s2_, s3_);       \
        }                                                                           \
      } else if (rm_ <= thr[row_]) { /* exact early-out: min_j > thr => none */     \
        const float sv_[4] = {s0_, s1_, s2_, s3_};                                  \
        _Pragma("unroll") for (int j = 0; j < 4; ++j) {                             \
          if (sv_[j] <= thr[row_]) {                                                \
            const int slot_ = atomicAdd(paircount, 1);                              \
            if (slot_ < CAP_PAIRS)                                                  \
              pairs[slot_] = ((unsigned)qrow[row_] << 13) |                         \
                             (unsigned)(k0_ + wn * 64 + j * 16 + col);              \
          }                                                                         \
        }                                                                           \
      }                                                                             \
    }                                                                               \
  } while (0)

  for (int nt = 0; nt < 7; ++nt) {
    ZEROACC;
#pragma unroll
    for (int ct = 0; ct < 8; ++ct) CHUNK(ct, true, nt * 8 + ct + 2, 2);
    SCORING(nt);
  }
  // nt = 7 epilogue: stop staging at chunk 63, then drain
  ZEROACC;
  CHUNK(0, true, 58, 2);
  CHUNK(1, true, 59, 2);
  CHUNK(2, true, 60, 2);
  CHUNK(3, true, 61, 2);
  CHUNK(4, true, 62, 2);
  CHUNK(5, true, 63, 2);
  CHUNK(6, false, 0, 0);
  CHUNK(7, false, 0, 3);
  SCORING(7);

#undef STAGE_B
#undef CHUNK
#undef ZEROACC
#undef SCORING

  if (PASS != 1) {
    // cross-col min (value only), then atomicMin per row
#pragma unroll
    for (int row = 0; row < 16; ++row) {
      float v = vmin[row];
      v = fminf(v, __shfl_xor(v, 1, 64));
      v = fminf(v, __shfl_xor(v, 2, 64));
      v = fminf(v, __shfl_xor(v, 4, 64));
      v = fminf(v, __shfl_xor(v, 8, 64));
      if (col == 0) atomicMin(&gmin[qrow[row]], f2mono(v));
    }
  }
}

__global__ __launch_bounds__(256, 2) void gemm_pass1(const char* __restrict__ At,
                                                     const char* __restrict__ Bt,
                                                     const float* __restrict__ cbnorm,
                                                     unsigned* __restrict__ gmin) {
  gemm_body<0>(At, Bt, cbnorm, gmin, nullptr, nullptr, nullptr);
}

__global__ __launch_bounds__(256, 2) void gemm_pass1s(const char* __restrict__ At,
                                                      const char* __restrict__ Bt,
                                                      const float* __restrict__ cbnorm,
                                                      unsigned* __restrict__ gmin,
                                                      unsigned* __restrict__ scores) {
  gemm_body<2>(At, Bt, cbnorm, gmin, nullptr, nullptr, scores);
}

__global__ __launch_bounds__(256, 2) void gemm_pass2(const char* __restrict__ At,
                                                     const char* __restrict__ Bt,
                                                     const float* __restrict__ cbnorm,
                                                     unsigned* __restrict__ gmin,
                                                     unsigned* __restrict__ pairs,
                                                     int* __restrict__ paircount) {
  gemm_body<1>(At, Bt, cbnorm, gmin, pairs, paircount, nullptr);
}

// ---------------------------------------------------------------------------
// scan_scores: stream the packed fp16 score matrix, push (q,k) for every
// stored score <= gmin[q] + MARGIN + F16STORE_ERR. Superset of the two-pass
// candidate set (stored = true + rtn_err, |rtn_err| <= ~5e-4 for |s|<1);
// exact_cand's fp32 rescore then picks the identical winner.
// ---------------------------------------------------------------------------
__global__ __launch_bounds__(256) void scan_scores(const unsigned* __restrict__ scores,
                                                   const unsigned* __restrict__ gmin,
                                                   unsigned* __restrict__ pairs,
                                                   int* __restrict__ paircount) {
  const unsigned NU4 = 16777216u;  // 2^26 uints / 4
  const unsigned stride = gridDim.x * blockDim.x;
  for (unsigned U = blockIdx.x * 256 + threadIdx.x; U < NU4; U += stride) {
    const uint4 v = ((const uint4*)scores)[U];
    const unsigned u = U << 2;
    const unsigned lane0 = u & 63;
    const unsigned e32 = (u >> 6) & 31;
    const unsigned wave = (u >> 11) & 3;
    const unsigned nt = (u >> 13) & 7;
    const unsigned blk = u >> 16;
    const unsigned mt = blk >> 3, slice = blk & 7;
    const unsigned wm = wave >> 1, wn = wave & 1;
    const unsigned i = e32 >> 3, r = (e32 >> 1) & 3, jp = e32 & 1;
    const unsigned quad = (lane0 >> 4) & 3, col0 = lane0 & 15;
    const int q = mt * 128 + wm * 64 + i * 16 + quad * 4 + r;
    const int kb = slice * 1024 + nt * 128 + wn * 64 + jp * 32 + col0;
    const float thr = mono2f(gmin[q]) + (MARGIN + F16STORE_ERR);
    const unsigned wv[4] = {v.x, v.y, v.z, v.w};
#pragma unroll
    for (int w = 0; w < 4; ++w) {
      const float slo = (float)__builtin_bit_cast(_Float16, (unsigned short)(wv[w] & 0xffffu));
      const float shi = (float)__builtin_bit_cast(_Float16, (unsigned short)(wv[w] >> 16));
      if (slo <= thr) {
        const int slot = atomicAdd(paircount, 1);
        if (slot < CAP_PAIRS) pairs[slot] = ((unsigned)q << 13) | (unsigned)(kb + w);
      }
      if (shi <= thr) {
        const int slot = atomicAdd(paircount, 1);
        if (slot < CAP_PAIRS) pairs[slot] = ((unsigned)q << 13) | (unsigned)(kb + 16 + w);
      }
    }
  }
}

// ---------------------------------------------------------------------------
// Exact fp32 rescore of all pushed pairs (np chain, R4-verified machinery).
// One wave per pair; winner per q via packed atomicMin (ties -> min k).
// ---------------------------------------------------------------------------
__global__ __launch_bounds__(256) void exact_cand(const float* __restrict__ zT,
                                                  const float* __restrict__ cb,
                                                  const float* __restrict__ cbnorm,
                                                  const float* __restrict__ znorm,
                                                  const unsigned* __restrict__ pairs,
                                                  const int* __restrict__ paircount,
                                                  unsigned long long* __restrict__ packed) {
  const int cnt = min(*paircount, CAP_PAIRS);
  const int gw = (blockIdx.x * 256 + threadIdx.x) >> 6;
  const int nw = (gridDim.x * 256) >> 6;
  const int lane = threadIdx.x & 63;
  for (int p = gw; p < cnt; p += nw) {
    const unsigned qk = pairs[p];
    const int q = qk >> 13, k = qk & 8191;
    const float4 cv = ((const float4*)(cb + (size_t)k * FEAT))[lane];
    const float4 zv = ((const float4*)(zT + (size_t)q * FEAT))[lane];
    float d = __builtin_fmaf(zv.w, cv.w,
              __builtin_fmaf(zv.z, cv.z,
              __builtin_fmaf(zv.y, cv.y, __fmul_rn(zv.x, cv.x))));
#pragma unroll
    for (int dd = 1; dd < 64; dd <<= 1) d = __fadd_rn(d, __shfl_xor(d, dd, 64));
    const float s = __fadd_rn(__fadd_rn(__fmul_rn(-2.0f, d), znorm[q]), cbnorm[k]);
    if (lane == 0) {
      const unsigned long long key = ((unsigned long long)f2mono(s) << 32) | (unsigned)k;
      atomicMin(&packed[q], key);
    }
  }
}

// ---------------------------------------------------------------------------
// Gather: zq[b][c][hw] = cb[idx]; idx as float appended after zq.
// ---------------------------------------------------------------------------
__global__ __launch_bounds__(256) void vq_gather(const float* __restrict__ cb,
                                                 const unsigned long long* __restrict__ packed,
                                                 float* __restrict__ out) {
  const int q0 = blockIdx.x * 64;
  const int nl = threadIdx.x & 63;
  const int cg = threadIdx.x >> 6;
  const int q = q0 + nl;
  const int kq = (int)((unsigned)packed[q] & 8191u);
  const int b = q >> 10, hw = q & 1023;
  const float4* cb4 = (const float4*)cb;
#pragma unroll
  for (int t = 0; t < 16; ++t) {
    const int cc = cg + t * 4;
    const float4 v = cb4[kq * 64 + cc];
    const int base = b * (FEAT * 1024) + (cc * 4) * 1024 + hw;
    out[base] = v.x;
    out[base + 1024] = v.y;
    out[base + 2048] = v.z;
    out[base + 3072] = v.w;
  }
  if (threadIdx.x < 64) {
    const int qq = q0 + threadIdx.x;
    out[ZQ_ELEMS + qq] = (float)(int)((unsigned)packed[qq] & 8191u);
  }
}

extern "C" void kernel_launch(void* const* d_in, const int* in_sizes, int n_in,
                              void* d_out, int out_size, void* d_ws, size_t ws_size,
                              hipStream_t stream) {
  const float* z = (const float*)d_in[0];
  const float* cb = (const float*)d_in[1];
  char* w = (char*)d_ws;
  // ws layout: 30.2 MB fixed + optional 256 MiB score matrix at 32 MB
  char* At = w;                                            // 8 MB
  char* Bt = w + 8388608;                                  // 4 MB
  float* zT = (float*)(w + 12582912);                      // 16 MB
  float* cbnorm = (float*)(w + 29360128);                  // 32 KB
  float* znorm = (float*)(w + 29392896);                   // 64 KB
  unsigned* gmin = (unsigned*)(w + 29458432);              // 64 KB
  int* paircount = (int*)(w + 29523968);                   // 256 B
  unsigned* pairs = (unsigned*)(w + 29524224);             // 512 KB
  unsigned long long* packed = (unsigned long long*)(w + 30048512);  // 128 KB
  unsigned* scores = (unsigned*)(w + SCORES_OFF);          // 256 MiB packed fp16x2

  const bool use_store = ws_size >= (size_t)(SCORES_OFF + SCORES_BYTES);

  hipMemsetAsync(paircount, 0, 256, stream);
  hipMemsetAsync(gmin, 0xFF, NQ * sizeof(unsigned), stream);
  hipMemsetAsync(packed, 0xFF, NQ * sizeof(unsigned long long), stream);
  norms_kernel<<<(CODES + NQ) / 16, 256, 0, stream>>>(cb, z, cbnorm, znorm);
  convA<<<1024, 256, 0, stream>>>(z, At, zT);
  convB<<<512, 256, 0, stream>>>(cb, Bt);
  if (use_store) {
    gemm_pass1s<<<(NQ / 128) * NSLICE, 256, 0, stream>>>(At, Bt, cbnorm, gmin, scores);
    scan_scores<<<2048, 256, 0, stream>>>(scores, gmin, pairs, paircount);
  } else {
    gemm_pass1<<<(NQ / 128) * NSLICE, 256, 0, stream>>>(At, Bt, cbnorm, gmin);
    gemm_pass2<<<(NQ / 128) * NSLICE, 256, 0, stream>>>(At, Bt, cbnorm, gmin, pairs, paircount);
  }
  exact_cand<<<512, 256, 0, stream>>>(zT, cb, cbnorm, znorm, pairs, paircount, packed);
  vq_gather<<<NQ / 64, 256, 0, stream>>>(cb, packed, (float*)d_out);
}